// Round 14
// baseline (145.843 us; speedup 1.0000x reference)
//
#include <hip/hip_runtime.h>

typedef __fp16 f16;
typedef __fp16 f16x2 __attribute__((ext_vector_type(2)));
typedef __fp16 f16x8 __attribute__((ext_vector_type(8)));
typedef float f32x4 __attribute__((ext_vector_type(4)));
typedef float f32x16 __attribute__((ext_vector_type(16)));

__device__ __forceinline__ unsigned pkrtz(float a, float b) {
    f16x2 r = __builtin_amdgcn_cvt_pkrtz(a, b);
    return __builtin_bit_cast(unsigned, r);
}

__device__ __forceinline__ f16x8 pack4(unsigned a, unsigned b, unsigned c, unsigned d) {
    union { unsigned u[4]; f16x8 v; } r;
    r.u[0] = a; r.u[1] = b; r.u[2] = c; r.u[3] = d;
    return r.v;
}

// Pack 30 weight matrices (64x64, row=k input, col=m output) into f16
// A-fragment order for v_mfma_f32_32x32x16_f16:
//   lane l holds A[m = l&31][k = 16*kt + 4*(l>>5) + (e&3) + 8*(e>=4)], mtile adds 32 to m.
__global__ __launch_bounds__(512) void pack_w(
    const float* __restrict__ sW1, const float* __restrict__ sW2, const float* __restrict__ sW3,
    const float* __restrict__ tW1, const float* __restrict__ tW2, const float* __restrict__ tW3,
    f16* __restrict__ wp) {
    int mat = blockIdx.x;            // layer*6 + {sW1,sW2,sW3,tW1,tW2,tW3}
    int layer = mat / 6;
    int rem = mat % 6;
    int fi = threadIdx.x >> 6;       // 0..7
    int lane = threadIdx.x & 63;
    int tile = fi >> 2, kt = fi & 3;
    int h = lane >> 5;
    int m = (lane & 31) + 32 * tile;
    const float* Wt[6] = {sW1, sW2, sW3, tW1, tW2, tW3};
    const float* W = Wt[rem] + layer * 4096;
    f16x8 v;
#pragma unroll
    for (int e = 0; e < 8; ++e) {
        int k = 16 * kt + 4 * h + (e & 3) + ((e >> 2) << 3);
        v[e] = (f16)W[k * 64 + m];
    }
    *(f16x8*)(wp + ((size_t)mat * 8 + fi) * 512 + lane * 8) = v;
}

// Pack 30 bias vectors (64 f32) into [layer][{s1,s2,s3,t1,t2,t3}][64] at wb.
__global__ __launch_bounds__(512) void pack_b(
    const float* __restrict__ sb1, const float* __restrict__ sb2, const float* __restrict__ sb3,
    const float* __restrict__ tb1, const float* __restrict__ tb2, const float* __restrict__ tb3,
    float* __restrict__ wb) {
    int i = blockIdx.x * 512 + threadIdx.x;
    if (i >= 1920) return;
    int l = i / 384, r = i % 384, mat = r / 64, j = r % 64;
    const float* B[6] = {sb1, sb2, sb3, tb1, tb2, tb3};
    wb[l * 384 + mat * 64 + j] = B[mat][l * 64 + j];
}

// bias pointer is LDS-resident (broadcast ds_read).
__device__ __forceinline__ void bias_init(const float* bias, int h, f32x16 c[2]) {
#pragma unroll
    for (int t = 0; t < 2; ++t) {
#pragma unroll
        for (int r4 = 0; r4 < 4; ++r4) {
            f32x4 bb = *(const f32x4*)(bias + 32 * t + 8 * r4 + 4 * h);
            c[t][4 * r4 + 0] = bb[0];
            c[t][4 * r4 + 1] = bb[1];
            c[t][4 * r4 + 2] = bb[2];
            c[t][4 * r4 + 3] = bb[3];
        }
    }
}

// Single-path 64x64 GEMM over a wave's 32 rows, weights+bias from LDS.
__device__ __forceinline__ void gemm1(const f16* w, const f16x8 in[4],
                                      const float* bias, int lane, f32x16 c[2]) {
    const int h = (lane >> 5) & 1;
    bias_init(bias, h, c);
#pragma unroll
    for (int mt = 0; mt < 2; ++mt) {
#pragma unroll
        for (int kt = 0; kt < 4; ++kt) {
            f16x8 wf = *(const f16x8*)(w + (mt * 4 + kt) * 512 + lane * 8);
            c[mt] = __builtin_amdgcn_mfma_f32_32x32x16_f16(wf, in[kt], c[mt], 0, 0, 0);
        }
    }
}

// leaky_relu (packed f16) + pack into next GEMM's B fragments.
// B-frag[kt][e] = C[mt = kt>>1][reg = 8*(kt&1) + e]  (register-local)
__device__ __forceinline__ void relu_pack(const f32x16 c[2], f16x8 o[4]) {
    const f16 hc = (f16)0.01f;
    const f16x8 c001 = {hc, hc, hc, hc, hc, hc, hc, hc};
#pragma unroll
    for (int kt = 0; kt < 4; ++kt) {
        const int tl = kt >> 1;
        const int base = 8 * (kt & 1);
        f16x8 v = pack4(pkrtz(c[tl][base + 0], c[tl][base + 1]),
                        pkrtz(c[tl][base + 2], c[tl][base + 3]),
                        pkrtz(c[tl][base + 4], c[tl][base + 5]),
                        pkrtz(c[tl][base + 6], c[tl][base + 7]));
        o[kt] = __builtin_elementwise_max(v, v * c001);   // v_pk_max / v_pk_mul
    }
}

// 3-GEMM MLP (one path), weights/biases from one LDS slot.
__device__ __forceinline__ void mlp3(const f16* w, const f16x8 x0f[4],
                                     int lane, f32x16 out[2]) {
    const float* bias = (const float*)(w + 12288);
    f32x16 c1[2];
    gemm1(w, x0f, bias, lane, c1);
    f16x8 h1[4];
    relu_pack(c1, h1);
    f32x16 c2[2];
    gemm1(w + 4096, h1, bias + 64, lane, c2);
    f16x8 h2[4];
    relu_pack(c2, h2);
    gemm1(w + 8192, h2, bias + 128, lane, out);
}

// Path slot: 12288 f16 weights + 192 f32 bias = 25344 B = 12672 f16 units.
#define SLOT 12672

__global__ __launch_bounds__(512, 2)
void flow_main(const float* __restrict__ x, const f16* __restrict__ wp,
               float* __restrict__ out, int nrows) {
    __shared__ f16 wl[3 * SLOT];   // 3 circular path slots, 76032 B -> 2 blocks/CU
    const int tid = threadIdx.x;
    const int lane = tid & 63;
    const int wv = tid >> 6;                                    // 0..7
    const int h = lane >> 5;
    const int n = (blockIdx.x * 8 + wv) * 32 + (lane & 31);     // 32 rows per wave
    const float* xr = x + (size_t)n * 128;
    float* zr = out + (size_t)n * 128;
    const float* wbias_g = (const float*)((const char*)wp + 491520);

    // Path p of layer l: weights at wp + l*24576 + p*12288, bias at wbias_g + l*384 + p*192.
    f32x4 stg[3];
    f32x4 stgb = {0.f, 0.f, 0.f, 0.f};

    // Prologue: stage s0 -> slot0, t0 -> slot1 synchronously.
#pragma unroll
    for (int p = 0; p < 2; ++p) {
        const f32x4* src = (const f32x4*)(wp + p * 12288);
#pragma unroll
        for (int i = 0; i < 3; ++i) stg[i] = src[tid + 512 * i];
        f32x4* dst = (f32x4*)(wl + p * SLOT);
#pragma unroll
        for (int i = 0; i < 3; ++i) dst[tid + 512 * i] = stg[i];
        if (tid < 48) {
            stgb = ((const f32x4*)(wbias_g + p * 192))[tid];
            ((f32x4*)(wl + p * SLOT + 12288))[tid] = stgb;
        }
    }

    // Load x0 (B-fragment gather), copy to z[:, :64], convert to f16 frags.
    f16x8 x0f[4];
#pragma unroll
    for (int kt = 0; kt < 4; ++kt) {
        f32x4 a = *(const f32x4*)(xr + 16 * kt + 4 * h);
        f32x4 b = *(const f32x4*)(xr + 16 * kt + 8 + 4 * h);
        *(f32x4*)(zr + 16 * kt + 4 * h) = a;
        *(f32x4*)(zr + 16 * kt + 8 + 4 * h) = b;
        x0f[kt] = pack4(pkrtz(a[0], a[1]), pkrtz(a[2], a[3]), pkrtz(b[0], b[1]), pkrtz(b[2], b[3]));
    }

    // x1 resident as packed f16 (16 regs). x1h[t*2+q][e] <-> feature 32t+16q+8*(e>=4)+4h+(e&3)
    f16x8 x1h[4];
#pragma unroll
    for (int i = 0; i < 4; ++i) {
        const int t = i >> 1, q = i & 1;
        f32x4 a = *(const f32x4*)(xr + 64 + 32 * t + 16 * q + 4 * h);
        f32x4 b = *(const f32x4*)(xr + 64 + 32 * t + 16 * q + 8 + 4 * h);
        x1h[i] = pack4(pkrtz(a[0], a[1]), pkrtz(a[2], a[3]),
                       pkrtz(b[0], b[1]), pkrtz(b[2], b[3]));
    }

    __syncthreads();

    float ld = 0.f;
#pragma unroll 1
    for (int l = 0; l < 5; ++l) {
        const int ss = (2 * l) % 3;
        const int ts = (2 * l + 1) % 3;
        const int fs = (2 * l + 2) % 3;   // free slot (next layer's s)

        // ---- s half ----
        if (l < 4) {   // prefetch s_{l+1} into regs (T14)
            const f32x4* src = (const f32x4*)(wp + (size_t)(l + 1) * 24576);
#pragma unroll
            for (int i = 0; i < 3; ++i) stg[i] = src[tid + 512 * i];
            if (tid < 48) stgb = ((const f32x4*)(wbias_g + (l + 1) * 384))[tid];
        }

        f32x16 cs[2];
        mlp3(wl + ss * SLOT, x0f, lane, cs);

        if (l < 4) {   // write s_{l+1} -> free slot (nobody reads it this layer)
            f32x4* dst = (f32x4*)(wl + fs * SLOT);
#pragma unroll
            for (int i = 0; i < 3; ++i) dst[tid + 512 * i] = stg[i];
            if (tid < 48) ((f32x4*)(wl + fs * SLOT + 12288))[tid] = stgb;
        }

        // tanh + logdet + x1 *= exp(s)
#pragma unroll
        for (int i = 0; i < 4; ++i) {
            const int t = i >> 1, q = i & 1;
            f16x8 xo = x1h[i];
            float nf[8];
#pragma unroll
            for (int e = 0; e < 8; ++e) {
                float y = cs[t][8 * q + e];
                float u = __builtin_amdgcn_exp2f(2.8853900817779268f * y);  // e^{2y}
                float rc = __builtin_amdgcn_rcpf(u + 1.f);
                float s = fmaf(-2.f, rc, 1.f);                              // tanh
                ld += s;
                float ef = __builtin_amdgcn_exp2f(fmaf(-2.8853900817779268f, rc, 1.4426950408889634f)); // e^{s}
                nf[e] = (float)xo[e] * ef;
            }
            x1h[i] = pack4(pkrtz(nf[0], nf[1]), pkrtz(nf[2], nf[3]),
                           pkrtz(nf[4], nf[5]), pkrtz(nf[6], nf[7]));
        }

        __syncthreads();   // barrier1: s-slot reads done; fs writes visible later

        // ---- t half ----
        if (l < 4) {   // prefetch t_{l+1} (t-path starts 12288 f16 into the layer block)
            const f32x4* src = (const f32x4*)(wp + (size_t)(l + 1) * 24576 + 12288);
#pragma unroll
            for (int i = 0; i < 3; ++i) stg[i] = src[tid + 512 * i];
            if (tid < 48) stgb = ((const f32x4*)(wbias_g + (l + 1) * 384 + 192))[tid];
        }

        f32x16 ct[2];
        mlp3(wl + ts * SLOT, x0f, lane, ct);

        if (l < 4) {   // write t_{l+1} over s_l's slot (dead after barrier1)
            f32x4* dst = (f32x4*)(wl + ss * SLOT);
#pragma unroll
            for (int i = 0; i < 3; ++i) dst[tid + 512 * i] = stg[i];
            if (tid < 48) ((f32x4*)(wl + ss * SLOT + 12288))[tid] = stgb;
        }

        // x1 += t
#pragma unroll
        for (int i = 0; i < 4; ++i) {
            const int t = i >> 1, q = i & 1;
            f16x8 xo = x1h[i];
            float nf[8];
#pragma unroll
            for (int e = 0; e < 8; ++e)
                nf[e] = (float)xo[e] + ct[t][8 * q + e];
            x1h[i] = pack4(pkrtz(nf[0], nf[1]), pkrtz(nf[2], nf[3]),
                           pkrtz(nf[4], nf[5]), pkrtz(nf[6], nf[7]));
        }

        __syncthreads();   // barrier2: t-slot reads done; ss writes visible next layer
    }

    // Store z[:, 64:]
#pragma unroll
    for (int i = 0; i < 4; ++i) {
        const int t = i >> 1, q = i & 1;
        f16x8 v = x1h[i];
        f32x4 a = {(float)v[0], (float)v[1], (float)v[2], (float)v[3]};
        f32x4 b = {(float)v[4], (float)v[5], (float)v[6], (float)v[7]};
        *(f32x4*)(zr + 64 + 32 * t + 16 * q + 4 * h) = a;
        *(f32x4*)(zr + 64 + 32 * t + 16 * q + 8 + 4 * h) = b;
    }

    // log_det: lane n holds half the features, lane n+32 the other half.
    float tot = ld + __shfl_xor(ld, 32);
    if (h == 0) out[(size_t)nrows * 128 + n] = tot;
}

extern "C" void kernel_launch(void* const* d_in, const int* in_sizes, int n_in,
                              void* d_out, int out_size, void* d_ws, size_t ws_size,
                              hipStream_t stream) {
    const float* x   = (const float*)d_in[0];
    const float* sW1 = (const float*)d_in[1];
    const float* sb1 = (const float*)d_in[2];
    const float* sW2 = (const float*)d_in[3];
    const float* sb2 = (const float*)d_in[4];
    const float* sW3 = (const float*)d_in[5];
    const float* sb3 = (const float*)d_in[6];
    const float* tW1 = (const float*)d_in[7];
    const float* tb1 = (const float*)d_in[8];
    const float* tW2 = (const float*)d_in[9];
    const float* tb2 = (const float*)d_in[10];
    const float* tW3 = (const float*)d_in[11];
    const float* tb3 = (const float*)d_in[12];

    f16* wp = (f16*)d_ws;      // weights: 240 KB frag-packed; biases: 7.5 KB at +480 KB
    float* wb = (float*)((char*)d_ws + 491520);
    int nrows = in_sizes[0] / 128;

    pack_w<<<30, 512, 0, stream>>>(sW1, sW2, sW3, tW1, tW2, tW3, wp);
    pack_b<<<4, 512, 0, stream>>>(sb1, sb2, sb3, tb1, tb2, tb3, wb);
    flow_main<<<nrows / 256, 512, 0, stream>>>(x, wp, (float*)d_out, nrows);
}

// Round 15
// 139.201 us; speedup vs baseline: 1.0477x; 1.0477x over previous
//
#include <hip/hip_runtime.h>

typedef __fp16 f16;
typedef __fp16 f16x2 __attribute__((ext_vector_type(2)));
typedef __fp16 f16x8 __attribute__((ext_vector_type(8)));
typedef float f32x4 __attribute__((ext_vector_type(4)));
typedef float f32x16 __attribute__((ext_vector_type(16)));

__device__ __forceinline__ unsigned pkrtz(float a, float b) {
    f16x2 r = __builtin_amdgcn_cvt_pkrtz(a, b);
    return __builtin_bit_cast(unsigned, r);
}

__device__ __forceinline__ f16x8 pack4(unsigned a, unsigned b, unsigned c, unsigned d) {
    union { unsigned u[4]; f16x8 v; } r;
    r.u[0] = a; r.u[1] = b; r.u[2] = c; r.u[3] = d;
    return r.v;
}

// Pack 30 weight matrices (64x64, row=k input, col=m output) into f16
// A-fragment order for v_mfma_f32_32x32x16_f16:
//   lane l holds A[m = l&31][k = 16*kt + 4*(l>>5) + (e&3) + 8*(e>=4)], mtile adds 32 to m.
__global__ __launch_bounds__(512) void pack_w(
    const float* __restrict__ sW1, const float* __restrict__ sW2, const float* __restrict__ sW3,
    const float* __restrict__ tW1, const float* __restrict__ tW2, const float* __restrict__ tW3,
    f16* __restrict__ wp) {
    int mat = blockIdx.x;            // layer*6 + {sW1,sW2,sW3,tW1,tW2,tW3}
    int layer = mat / 6;
    int rem = mat % 6;
    int fi = threadIdx.x >> 6;       // 0..7
    int lane = threadIdx.x & 63;
    int tile = fi >> 2, kt = fi & 3;
    int h = lane >> 5;
    int m = (lane & 31) + 32 * tile;
    const float* Wt[6] = {sW1, sW2, sW3, tW1, tW2, tW3};
    const float* W = Wt[rem] + layer * 4096;
    f16x8 v;
#pragma unroll
    for (int e = 0; e < 8; ++e) {
        int k = 16 * kt + 4 * h + (e & 3) + ((e >> 2) << 3);
        v[e] = (f16)W[k * 64 + m];
    }
    *(f16x8*)(wp + ((size_t)mat * 8 + fi) * 512 + lane * 8) = v;
}

// Pack 30 bias vectors (64 f32) into [layer][{s1,s2,s3,t1,t2,t3}][64] at wb.
__global__ __launch_bounds__(512) void pack_b(
    const float* __restrict__ sb1, const float* __restrict__ sb2, const float* __restrict__ sb3,
    const float* __restrict__ tb1, const float* __restrict__ tb2, const float* __restrict__ tb3,
    float* __restrict__ wb) {
    int i = blockIdx.x * 512 + threadIdx.x;
    if (i >= 1920) return;
    int l = i / 384, r = i % 384, mat = r / 64, j = r % 64;
    const float* B[6] = {sb1, sb2, sb3, tb1, tb2, tb3};
    wb[l * 384 + mat * 64 + j] = B[mat][l * 64 + j];
}

// bias pointer is LDS-resident (broadcast ds_read).
__device__ __forceinline__ void bias_init(const float* bias, int h, f32x16 c[2]) {
#pragma unroll
    for (int t = 0; t < 2; ++t) {
#pragma unroll
        for (int r4 = 0; r4 < 4; ++r4) {
            f32x4 bb = *(const f32x4*)(bias + 32 * t + 8 * r4 + 4 * h);
            c[t][4 * r4 + 0] = bb[0];
            c[t][4 * r4 + 1] = bb[1];
            c[t][4 * r4 + 2] = bb[2];
            c[t][4 * r4 + 3] = bb[3];
        }
    }
}

// Single-path 64x64 GEMM over a wave's 32 rows, weights+bias from LDS.
__device__ __forceinline__ void gemm1(const f16* w, const f16x8 in[4],
                                      const float* bias, int lane, f32x16 c[2]) {
    const int h = (lane >> 5) & 1;
    bias_init(bias, h, c);
#pragma unroll
    for (int mt = 0; mt < 2; ++mt) {
#pragma unroll
        for (int kt = 0; kt < 4; ++kt) {
            f16x8 wf = *(const f16x8*)(w + (mt * 4 + kt) * 512 + lane * 8);
            c[mt] = __builtin_amdgcn_mfma_f32_32x32x16_f16(wf, in[kt], c[mt], 0, 0, 0);
        }
    }
}

// leaky_relu (packed f16) + pack into next GEMM's B fragments.
// B-frag[kt][e] = C[mt = kt>>1][reg = 8*(kt&1) + e]  (register-local)
__device__ __forceinline__ void relu_pack(const f32x16 c[2], f16x8 o[4]) {
    const f16 hc = (f16)0.01f;
    const f16x8 c001 = {hc, hc, hc, hc, hc, hc, hc, hc};
#pragma unroll
    for (int kt = 0; kt < 4; ++kt) {
        const int tl = kt >> 1;
        const int base = 8 * (kt & 1);
        f16x8 v = pack4(pkrtz(c[tl][base + 0], c[tl][base + 1]),
                        pkrtz(c[tl][base + 2], c[tl][base + 3]),
                        pkrtz(c[tl][base + 4], c[tl][base + 5]),
                        pkrtz(c[tl][base + 6], c[tl][base + 7]));
        o[kt] = __builtin_elementwise_max(v, v * c001);   // v_pk_max / v_pk_mul
    }
}

// 3-GEMM MLP (one path), weights/biases from the LDS slot.
__device__ __forceinline__ void mlp3(const f16* w, const f16x8 x0f[4],
                                     int lane, f32x16 out[2]) {
    const float* bias = (const float*)(w + 12288);
    f32x16 c1[2];
    gemm1(w, x0f, bias, lane, c1);
    f16x8 h1[4];
    relu_pack(c1, h1);
    f32x16 c2[2];
    gemm1(w + 4096, h1, bias + 64, lane, c2);
    f16x8 h2[4];
    relu_pack(c2, h2);
    gemm1(w + 8192, h2, bias + 128, lane, out);
}

// Path slot: 12288 f16 weights + 192 f32 bias = 25344 B.
#define SLOT 12672

__global__ __launch_bounds__(512, 2)
void flow_main(const float* __restrict__ x, const f16* __restrict__ wp,
               float* __restrict__ out, int nrows) {
    __shared__ f16 wl[SLOT];   // ONE path slot, 25344 B -> 2 blocks/CU
    const int tid = threadIdx.x;
    const int lane = tid & 63;
    const int wv = tid >> 6;                                    // 0..7
    const int h = lane >> 5;
    const int n = (blockIdx.x * 8 + wv) * 32 + (lane & 31);     // 32 rows per wave
    const float* xr = x + (size_t)n * 128;
    float* zr = out + (size_t)n * 128;
    const float* wbias_g = (const float*)((const char*)wp + 491520);

    // Path p of layer l: weights at wp + l*24576 + p*12288, bias at wbias_g + l*384 + p*192.
    f32x4 stg0, stg1, stg2;
    f32x4 stgb = {0.f, 0.f, 0.f, 0.f};

    // Prologue: stage s0 -> slot synchronously.
    {
        const f32x4* src = (const f32x4*)wp;
        stg0 = src[tid]; stg1 = src[tid + 512]; stg2 = src[tid + 1024];
        f32x4* dst = (f32x4*)wl;
        dst[tid] = stg0; dst[tid + 512] = stg1; dst[tid + 1024] = stg2;
        if (tid < 48) {
            stgb = ((const f32x4*)wbias_g)[tid];
            ((f32x4*)(wl + 12288))[tid] = stgb;
        }
    }

    // Load x0 (B-fragment gather), copy to z[:, :64], convert to f16 frags.
    f16x8 x0f[4];
#pragma unroll
    for (int kt = 0; kt < 4; ++kt) {
        f32x4 a = *(const f32x4*)(xr + 16 * kt + 4 * h);
        f32x4 b = *(const f32x4*)(xr + 16 * kt + 8 + 4 * h);
        *(f32x4*)(zr + 16 * kt + 4 * h) = a;
        *(f32x4*)(zr + 16 * kt + 8 + 4 * h) = b;
        x0f[kt] = pack4(pkrtz(a[0], a[1]), pkrtz(a[2], a[3]), pkrtz(b[0], b[1]), pkrtz(b[2], b[3]));
    }

    // x1 resident as packed f16 (16 regs). x1h[t*2+q][e] <-> feature 32t+16q+8*(e>=4)+4h+(e&3)
    f16x8 x1h[4];
#pragma unroll
    for (int i = 0; i < 4; ++i) {
        const int t = i >> 1, q = i & 1;
        f32x4 a = *(const f32x4*)(xr + 64 + 32 * t + 16 * q + 4 * h);
        f32x4 b = *(const f32x4*)(xr + 64 + 32 * t + 16 * q + 8 + 4 * h);
        x1h[i] = pack4(pkrtz(a[0], a[1]), pkrtz(a[2], a[3]),
                       pkrtz(b[0], b[1]), pkrtz(b[2], b[3]));
    }

    __syncthreads();

    float ld = 0.f;
#pragma unroll 1
    for (int l = 0; l < 5; ++l) {
        // ---- s phase (slot holds s_l) ----
        {   // prefetch t_l into regs (T14: hides under s-MLP)
            const f32x4* src = (const f32x4*)(wp + (size_t)l * 24576 + 12288);
            stg0 = src[tid]; stg1 = src[tid + 512]; stg2 = src[tid + 1024];
            if (tid < 48) stgb = ((const f32x4*)(wbias_g + l * 384 + 192))[tid];
        }

        f32x16 cs[2];
        mlp3(wl, x0f, lane, cs);

        // tanh + logdet + x1 *= exp(s)
#pragma unroll
        for (int i = 0; i < 4; ++i) {
            const int t = i >> 1, q = i & 1;
            f16x8 xo = x1h[i];
            float nf[8];
#pragma unroll
            for (int e = 0; e < 8; ++e) {
                float y = cs[t][8 * q + e];
                float u = __builtin_amdgcn_exp2f(2.8853900817779268f * y);  // e^{2y}
                float rc = __builtin_amdgcn_rcpf(u + 1.f);
                float s = fmaf(-2.f, rc, 1.f);                              // tanh
                ld += s;
                float ef = __builtin_amdgcn_exp2f(fmaf(-2.8853900817779268f, rc, 1.4426950408889634f)); // e^{s}
                nf[e] = (float)xo[e] * ef;
            }
            x1h[i] = pack4(pkrtz(nf[0], nf[1]), pkrtz(nf[2], nf[3]),
                           pkrtz(nf[4], nf[5]), pkrtz(nf[6], nf[7]));
        }

        __syncthreads();   // all waves done reading s_l
        {   // write t_l -> slot
            f32x4* dst = (f32x4*)wl;
            dst[tid] = stg0; dst[tid + 512] = stg1; dst[tid + 1024] = stg2;
            if (tid < 48) ((f32x4*)(wl + 12288))[tid] = stgb;
        }
        __syncthreads();   // t_l visible

        // ---- t phase (slot holds t_l) ----
        if (l < 4) {   // prefetch s_{l+1}
            const f32x4* src = (const f32x4*)(wp + (size_t)(l + 1) * 24576);
            stg0 = src[tid]; stg1 = src[tid + 512]; stg2 = src[tid + 1024];
            if (tid < 48) stgb = ((const f32x4*)(wbias_g + (l + 1) * 384))[tid];
        }

        f32x16 ct[2];
        mlp3(wl, x0f, lane, ct);

        // x1 += t
#pragma unroll
        for (int i = 0; i < 4; ++i) {
            const int t = i >> 1, q = i & 1;
            f16x8 xo = x1h[i];
            float nf[8];
#pragma unroll
            for (int e = 0; e < 8; ++e)
                nf[e] = (float)xo[e] + ct[t][8 * q + e];
            x1h[i] = pack4(pkrtz(nf[0], nf[1]), pkrtz(nf[2], nf[3]),
                           pkrtz(nf[4], nf[5]), pkrtz(nf[6], nf[7]));
        }

        if (l < 4) {
            __syncthreads();   // all waves done reading t_l
            {   // write s_{l+1} -> slot
                f32x4* dst = (f32x4*)wl;
                dst[tid] = stg0; dst[tid + 512] = stg1; dst[tid + 1024] = stg2;
                if (tid < 48) ((f32x4*)(wl + 12288))[tid] = stgb;
            }
            __syncthreads();   // s_{l+1} visible
        }
    }

    // Store z[:, 64:]
#pragma unroll
    for (int i = 0; i < 4; ++i) {
        const int t = i >> 1, q = i & 1;
        f16x8 v = x1h[i];
        f32x4 a = {(float)v[0], (float)v[1], (float)v[2], (float)v[3]};
        f32x4 b = {(float)v[4], (float)v[5], (float)v[6], (float)v[7]};
        *(f32x4*)(zr + 64 + 32 * t + 16 * q + 4 * h) = a;
        *(f32x4*)(zr + 64 + 32 * t + 16 * q + 8 + 4 * h) = b;
    }

    // log_det: lane n holds half the features, lane n+32 the other half.
    float tot = ld + __shfl_xor(ld, 32);
    if (h == 0) out[(size_t)nrows * 128 + n] = tot;
}

extern "C" void kernel_launch(void* const* d_in, const int* in_sizes, int n_in,
                              void* d_out, int out_size, void* d_ws, size_t ws_size,
                              hipStream_t stream) {
    const float* x   = (const float*)d_in[0];
    const float* sW1 = (const float*)d_in[1];
    const float* sb1 = (const float*)d_in[2];
    const float* sW2 = (const float*)d_in[3];
    const float* sb2 = (const float*)d_in[4];
    const float* sW3 = (const float*)d_in[5];
    const float* sb3 = (const float*)d_in[6];
    const float* tW1 = (const float*)d_in[7];
    const float* tb1 = (const float*)d_in[8];
    const float* tW2 = (const float*)d_in[9];
    const float* tb2 = (const float*)d_in[10];
    const float* tW3 = (const float*)d_in[11];
    const float* tb3 = (const float*)d_in[12];

    f16* wp = (f16*)d_ws;      // weights: 240 KB frag-packed; biases: 7.5 KB at +480 KB
    float* wb = (float*)((char*)d_ws + 491520);
    int nrows = in_sizes[0] / 128;

    pack_w<<<30, 512, 0, stream>>>(sW1, sW2, sW3, tW1, tW2, tW3, wp);
    pack_b<<<4, 512, 0, stream>>>(sb1, sb2, sb3, tb1, tb2, tb3, wb);
    flow_main<<<nrows / 256, 512, 0, stream>>>(x, wp, (float*)d_out, nrows);
}